// Round 1
// 165.015 us; speedup vs baseline: 1.0555x; 1.0555x over previous
//
#include <hip/hip_runtime.h>
#include <hip/hip_bf16.h>
#include <math.h>

#define B_ 32
#define S_ 64
#define T_ 256
#define L_ 8
#define D_ 128
#define H_ 128

typedef __attribute__((ext_vector_type(8))) short short8;
typedef __attribute__((ext_vector_type(4))) short short4v;
typedef __attribute__((ext_vector_type(4))) float float4v;
typedef __attribute__((ext_vector_type(4))) int int4v;

__device__ __forceinline__ short f2bf(float x) {
  __hip_bfloat16 h = __float2bfloat16(x);
  return *reinterpret_cast<short*>(&h);
}

// lane-uniform broadcast of lane `sl` (sl must be wave-uniform): v_readlane
__device__ __forceinline__ float rdlane(float x, int sl) {
  return __int_as_float(__builtin_amdgcn_readlane(__float_as_int(x), sl));
}
// shift down by one lane across the whole wave (DPP wave_shr:1);
// lane 0 receives `tailv` (old-value path, bound_ctrl=0)
__device__ __forceinline__ float dpp_shr1(float x, float tailv) {
  int r = __builtin_amdgcn_update_dpp(__float_as_int(tailv), __float_as_int(x),
                                      0x138, 0xF, 0xF, false);
  return __int_as_float(r);
}

// ---------------------------------------------------------------------------
// Stage A (+prep merged): blocks 0-7: Toeplitz-Schur Cholesky, one wave per
// latent l. Coefficient chain shortened: r = rsqrt(u_k^2 - v_k^2),
// s = u_k*r, sr = v_k*r  (identical algebra to rho/1-rho^2 form, one
// transcendental on the serial chain instead of two).
// Blocks 8-71: weight conversion. W1T slot c now holds W1 column
// m(c) = 32*(c>>5) + 2*(c&15) + ((c>>4)&1)  (H-permutation so decode's two
// per-lane h outputs land in ADJACENT hS columns -> packed bf16x2 store).
// W2T rows are indexed by physical h = m, which equals the logical column, so
// W2T build is unchanged.
// ---------------------------------------------------------------------------
__global__ __launch_bounds__(64) void k_chol_prep(
    const float* __restrict__ times, const float* __restrict__ log_taus,
    __hip_bfloat16* __restrict__ Lcbf_,
    const float* __restrict__ W1, const float* __restrict__ W2,
    __hip_bfloat16* __restrict__ W1T, __hip_bfloat16* __restrict__ W2T)
{
  __shared__ short panel[256][68];
  const int bi = blockIdx.x;
  const int j = threadIdx.x;

  if (bi >= 8) {
    const int base = (bi - 8) * 64 + j;          // 0..4095
    for (int idx = base; idx < H_ * D_; idx += 4096) {
      const int cc = idx >> 7, h = idx & 127;
      const int n = cc & 15, nt = cc >> 4;
      const int d = n * 8 + nt;
      W2T[(size_t)cc * H_ + h] = __float2bfloat16(W2[(size_t)h * D_ + d]);
    }
    for (int idx = base; idx < L_ * H_; idx += 4096) {
      const int li = idx >> 7, h = idx & 127;
      const int msrc = 32 * (h >> 5) + 2 * (h & 15) + ((h >> 4) & 1);
      W1T[(size_t)h * L_ + li] = __float2bfloat16(W1[(size_t)li * H_ + msrc]);
    }
    return;
  }

  const int l = bi;
  short* Lbf = (short*)Lcbf_ + (size_t)l * T_ * T_;

  const float tau = expf(log_taus[l]);
  const float inv2tau2 = 0.5f / (tau * tau);
  const float sig2 = 0.999f * 0.999f;
  const float t0 = times[0];

  const float c0 = sig2 + 1e-4f;
  const float isc0 = 1.0f / sqrtf(c0);

  float u[4], v[4];
#pragma unroll
  for (int c = 0; c < 4; ++c) {
    const int d = c * 64 + j;
    const float dt = times[d] - t0;
    float cv = sig2 * __expf(-dt * dt * inv2tau2);
    if (d == 0) cv = c0;
    u[c] = cv * isc0;
    v[c] = (d == 0) ? 0.0f : u[c];
  }

#pragma unroll
  for (int p = 0; p < 4; ++p) {
    for (int kk = 0; kk < 64; ++kk) {
      const float uk = rdlane(u[p], kk);
      const float vk = rdlane(v[p], kk);
      const float dd = fmaxf(__builtin_fmaf(uk, uk, -vk * vk), 1e-20f);
      const float rr = __builtin_amdgcn_rsqf(dd);
      const float s = uk * rr;
      const float sr = vk * rr;

      float up[4];
#pragma unroll
      for (int c = 0; c < 4; ++c) {
        if (c >= p) {
          const float uc = u[c], vc = v[c];
          up[c] = s * uc - sr * vc;
          v[c]  = s * vc - sr * uc;
          const float val = (c > p || j >= kk) ? up[c] : 0.0f;
          panel[(c - p) * 64 + j][kk] = f2bf(val);
        }
      }
#pragma unroll
      for (int c = 3; c >= 0; --c) {
        if (c >= p) {
          const float tail = (c > p) ? rdlane(up[c - 1], 63) : 0.0f;
          u[c] = dpp_shr1(up[c], tail);
        }
      }
    }
    __syncthreads();
    const int rpt = 256 - 64 * p;
    const int rsub = j >> 4, cp = (j & 15) * 4;
    for (int i0 = 0; i0 < rpt; i0 += 4) {
      const int pr = i0 + rsub;
      short4v vv = *(const short4v*)&panel[pr][cp];
      *(short4v*)&Lbf[((size_t)(p * 64 + pr) << 8) + p * 64 + cp] = vv;
    }
    __syncthreads();
  }
}

// ---------------------------------------------------------------------------
// Stage B: z GEMM via bf16 MFMA. Block = (l, bs-tile of 32) -> 512 blocks
// (2 blocks/CU for phase overlap). Pair-balanced triangular tiles: wave w
// owns 16-row tiles {w, 15-w, 7-w, 8+w} -> exactly 36 MFMA per wave (was
// 32..128, 4:1 imbalance). Output layout Zg[l][bs][t]: acc is transposed
// through the E LDS buffer after the K-loop and written as DENSE short8
// stores (old [bs][t][l] layout forced isolated 2B scatter stores, ~64
// cache lines per wave-store).
// ---------------------------------------------------------------------------
__global__ __launch_bounds__(256) void k_zgemm(
    const float* __restrict__ eps, const __hip_bfloat16* __restrict__ Lcbf_,
    __hip_bfloat16* __restrict__ Zg)
{
  __shared__ __align__(16) short E[32][264];
  const int bi = blockIdx.x;
  const int l = bi & 7, bs0 = (bi >> 3) * 32;
  const int tid = threadIdx.x, w = tid >> 6, lane = tid & 63;
  const int n = lane & 15, q = lane >> 4;
  const short* Lb = (const short*)Lcbf_ + (size_t)l * T_ * T_;

  // stage eps[bs0+row][l][:] -> E[row][:] bf16 (4 lanes cover 64B runs)
  {
    const int row = tid >> 3, part = tid & 7;
    const float* src = eps + ((size_t)(bs0 + row) * L_ + l) * T_;
#pragma unroll
    for (int g = 0; g < 8; ++g) {
      const int c = (part + g * 8) * 4;
      float4v f = *(const float4v*)(src + c);
      short4v o;
#pragma unroll
      for (int jj = 0; jj < 4; ++jj) o[jj] = f2bf(f[jj]);
      *(short4v*)&E[row][c] = o;
    }
  }
  __syncthreads();

  float4v acc[4][2];
#pragma unroll
  for (int mi = 0; mi < 4; ++mi)
#pragma unroll
    for (int nt = 0; nt < 2; ++nt) acc[mi][nt] = (float4v){0.f, 0.f, 0.f, 0.f};

  // per-tile K bound: kc(t) = 32*ceil(16(t+1)/32); stays within the
  // chol-zeroed panel region (kc <= 64*(panel+1) for every tile).
  const int kmax = ((15 - w + 2) >> 1) << 5;      // w: 256,256,224,224
  for (int k0 = 0; k0 < kmax; k0 += 32) {
    short8 bfrg[2];
#pragma unroll
    for (int nt = 0; nt < 2; ++nt)
      bfrg[nt] = *(const short8*)&E[nt * 16 + n][k0 + q * 8];
#pragma unroll
    for (int mi = 0; mi < 4; ++mi) {
      const int tile = (mi == 0) ? w : (mi == 1) ? (15 - w) : (mi == 2) ? (7 - w) : (8 + w);
      const int kc = ((tile + 2) >> 1) << 5;
      if (k0 < kc) {
        const int u = tile * 16 + n;
        const short8 afr = *(const short8*)&Lb[((size_t)u << 8) + k0 + q * 8];
#pragma unroll
        for (int nt = 0; nt < 2; ++nt)
          acc[mi][nt] = __builtin_amdgcn_mfma_f32_16x16x32_bf16(afr, bfrg[nt], acc[mi][nt], 0, 0, 0);
      }
    }
  }
  __syncthreads();   // all waves done reading E -> reuse as transpose buffer

#pragma unroll
  for (int mi = 0; mi < 4; ++mi) {
    const int tile = (mi == 0) ? w : (mi == 1) ? (15 - w) : (mi == 2) ? (7 - w) : (8 + w);
#pragma unroll
    for (int nt = 0; nt < 2; ++nt) {
      short4v o;
#pragma unroll
      for (int r = 0; r < 4; ++r) o[r] = f2bf(acc[mi][nt][r]);
      *(short4v*)&E[nt * 16 + n][tile * 16 + q * 4] = o;
    }
  }
  __syncthreads();

  // dense coalesced copy: Zg[l][bs][t]
  {
    const int row = tid >> 3, part = tid & 7;
    short* dst = (short*)Zg + ((size_t)l * (B_ * S_) + bs0 + row) * T_;
#pragma unroll
    for (int g = 0; g < 4; ++g) {
      const int c = (g * 8 + part) * 8;
      *(short8*)&dst[c] = *(const short8*)&E[row][c];
    }
  }
}

// ---------------------------------------------------------------------------
// Stages C-F fused: one block per (b,s). Quarter-phased hS (64 t-rows per
// phase) cuts LDS 39.4KB -> 21.5KB => 7 blocks/CU (28 of 32 waves, was 16).
// H-permuted W1T makes each lane's two h outputs adjacent: one packed
// bf16x2 LDS store (2-way bank alias = free; old 2x b16 stores were 4-way
// conflicted). exp folded: exp(2(c+b)) = exp2(fma(c, 2log2e, pb)).
// ---------------------------------------------------------------------------
__global__ __launch_bounds__(256, 7) void k_decode(
    const float* __restrict__ X, const __hip_bfloat16* __restrict__ Zg,
    const __hip_bfloat16* __restrict__ W1T, const float* __restrict__ b1,
    const __hip_bfloat16* __restrict__ W2T, const float* __restrict__ b2,
    const float* __restrict__ log_R, float* __restrict__ ll)
{
  __shared__ __align__(16) short Zt[256][8];
  __shared__ __align__(16) __hip_bfloat16 hS[64][136];
  __shared__ float redbuf[4];

  const int bs = blockIdx.x;
  const int b = bs >> 6;
  const int tid = threadIdx.x;
  const int w = tid >> 6, lane = tid & 63;
  const int n = lane & 15, q = lane >> 4;
  const unsigned short* Zs = (const unsigned short*)Zg;
  const short* W1s = (const short*)W1T;
  const short* W2s = (const short*)W2T;

  // gather Z[t=tid][l=0..7] from [l][bs][t] (each load coalesced 512B/wave)
  {
    const size_t base = (size_t)bs * T_ + tid;
    const size_t lstr = (size_t)(B_ * S_) * T_;
    unsigned int p0 = (unsigned int)Zs[base]            | ((unsigned int)Zs[base + lstr]     << 16);
    unsigned int p1 = (unsigned int)Zs[base + 2 * lstr] | ((unsigned int)Zs[base + 3 * lstr] << 16);
    unsigned int p2 = (unsigned int)Zs[base + 4 * lstr] | ((unsigned int)Zs[base + 5 * lstr] << 16);
    unsigned int p3 = (unsigned int)Zs[base + 6 * lstr] | ((unsigned int)Zs[base + 7 * lstr] << 16);
    int4v zi = {(int)p0, (int)p1, (int)p2, (int)p3};
    *(int4v*)&Zt[tid][0] = zi;
  }

  float sLR = log_R[lane] + log_R[lane + 64];
#pragma unroll
  for (int off = 32; off >= 1; off >>= 1) sLR += __shfl_xor(sLR, off);

  const float L22 = 2.8853900817779268f;   // 2*log2(e)
  const int d0 = n * 8 + 2 * w;
  const int hc = 32 * w + 2 * n;           // physical hS column pair base
  float invr2[2], b22[2], pb[2];
#pragma unroll
  for (int jj = 0; jj < 2; ++jj) {
    invr2[jj] = expf(-log_R[d0 + jj]);
    b22[jj] = b2[d0 + jj];
    pb[jj] = b1[hc + jj] * L22;
  }

  const short8 zero8 = {0, 0, 0, 0, 0, 0, 0, 0};
  short8 w1f[2];
  short8 bfr[2][4];
#pragma unroll
  for (int jj = 0; jj < 2; ++jj) {
    const int c = (2 * w + jj) * 16 + n;
    short8 v = zero8;
    if (q == 0) v = *(const short8*)&W1s[(size_t)c * L_];
    w1f[jj] = v;
#pragma unroll
    for (int ks = 0; ks < 4; ++ks)
      bfr[jj][ks] = *(const short8*)&W2s[(size_t)c * H_ + ks * 32 + q * 8];
  }

  float qsum = 0.0f;
  __syncthreads();   // Zt ready

#pragma unroll 1
  for (int qtr = 0; qtr < 4; ++qtr) {
    short* hp = (short*)hS + (q * 4) * 136 + hc;
#pragma unroll 1
    for (int mi = 0; mi < 4; ++mi) {
      short8 zf = zero8;
      if (q == 0) zf = *(const short8*)&Zt[qtr * 64 + mi * 16 + n][0];
      float4v c0 = __builtin_amdgcn_mfma_f32_16x16x32_bf16(zf, w1f[0], (float4v){0.f,0.f,0.f,0.f}, 0, 0, 0);
      float4v c1 = __builtin_amdgcn_mfma_f32_16x16x32_bf16(zf, w1f[1], (float4v){0.f,0.f,0.f,0.f}, 0, 0, 0);
#pragma unroll
      for (int r = 0; r < 4; ++r) {
        const float a0 = __builtin_fmaf(c0[r], L22, pb[0]);
        const float a1 = __builtin_fmaf(c1[r], L22, pb[1]);
        const float p0 = __builtin_amdgcn_exp2f(a0) + 1.f;
        const float p1 = __builtin_amdgcn_exp2f(a1) + 1.f;
        const float rj = __builtin_amdgcn_rcpf(p0 * p1);
        const float h0 = __builtin_fmaf(-2.f * p1, rj, 1.f);
        const float h1 = __builtin_fmaf(-2.f * p0, rj, 1.f);
        float2 hv2; hv2.x = h0; hv2.y = h1;
        *reinterpret_cast<__hip_bfloat162*>(hp + r * 136) = __float22bfloat162_rn(hv2);
      }
      hp += 16 * 136;
    }
    __syncthreads();
#pragma unroll 1
    for (int mi = 0; mi < 4; ++mi) {
      short8 af[4];
#pragma unroll
      for (int ks = 0; ks < 4; ++ks)
        af[ks] = *(const short8*)&hS[mi * 16 + n][ks * 32 + q * 8];
      float4v acc0 = (float4v){0.f, 0.f, 0.f, 0.f};
      float4v acc1 = (float4v){0.f, 0.f, 0.f, 0.f};
#pragma unroll
      for (int ks = 0; ks < 4; ++ks) {
        acc0 = __builtin_amdgcn_mfma_f32_16x16x32_bf16(af[ks], bfr[0][ks], acc0, 0, 0, 0);
        acc1 = __builtin_amdgcn_mfma_f32_16x16x32_bf16(af[ks], bfr[1][ks], acc1, 0, 0, 0);
      }
      const int tbase = qtr * 64 + mi * 16 + q * 4;
#pragma unroll
      for (int r = 0; r < 4; ++r) {
        const int t = tbase + r;
        const float2 xv = *(const float2*)(X + (((size_t)b << 8) + t) * D_ + d0);
        float diff0 = xv.x - (acc0[r] + b22[0]);
        float diff1 = xv.y - (acc1[r] + b22[1]);
        qsum += diff0 * diff0 * invr2[0] + diff1 * diff1 * invr2[1];
      }
    }
    __syncthreads();
  }

#pragma unroll
  for (int off = 32; off >= 1; off >>= 1) qsum += __shfl_xor(qsum, off);
  if (lane == 0) redbuf[w] = qsum;
  __syncthreads();
  if (tid == 0) {
    float Q = redbuf[0] + redbuf[1] + redbuf[2] + redbuf[3];
    float log_norm = 0.5f * (sLR + (float)D_ * 1.8378770664093453f);
    ll[bs] = -0.5f * Q - (float)T_ * log_norm;
  }
}

// ---------------------------------------------------------------------------
// Final: nll[b] = -(logsumexp_s(ll) - log S). One wave per b.
// ---------------------------------------------------------------------------
__global__ __launch_bounds__(64) void k_lse(
    const float* __restrict__ ll, float* __restrict__ out)
{
  const int b = blockIdx.x;
  const int s = threadIdx.x;
  float v = ll[b * 64 + s];
  float m = v;
#pragma unroll
  for (int off = 32; off >= 1; off >>= 1) m = fmaxf(m, __shfl_xor(m, off));
  float e = __expf(v - m);
#pragma unroll
  for (int off = 32; off >= 1; off >>= 1) e += __shfl_xor(e, off);
  if (s == 0) out[b] = -(m + __logf(e) - 4.1588830833596715f);
}

extern "C" void kernel_launch(void* const* d_in, const int* in_sizes, int n_in,
                              void* d_out, int out_size, void* d_ws, size_t ws_size,
                              hipStream_t stream) {
  const float* X        = (const float*)d_in[0];
  const float* times    = (const float*)d_in[1];
  const float* log_taus = (const float*)d_in[2];
  const float* log_R    = (const float*)d_in[3];
  const float* W1       = (const float*)d_in[4];
  const float* b1       = (const float*)d_in[5];
  const float* W2       = (const float*)d_in[6];
  const float* b2       = (const float*)d_in[7];
  const float* eps      = (const float*)d_in[8];
  float* out = (float*)d_out;

  char* ws = (char*)d_ws;
  __hip_bfloat16* Lcbf = (__hip_bfloat16*)(ws);                // 1 MiB bf16 [L][T][T]
  __hip_bfloat16* Zg   = (__hip_bfloat16*)(ws + 1048576);      // 8 MiB bf16 [L][BS][T]
  float* ll            = (float*)(ws + 9437184);               // 8 KiB
  __hip_bfloat16* W2T  = (__hip_bfloat16*)(ws + 9445376);      // 32 KiB
  __hip_bfloat16* W1T  = (__hip_bfloat16*)(ws + 9478144);      // 2 KiB

  hipLaunchKernelGGL(k_chol_prep, dim3(72),   dim3(64),  0, stream,
                     times, log_taus, Lcbf, W1, W2, W1T, W2T);
  hipLaunchKernelGGL(k_zgemm,     dim3(512),  dim3(256), 0, stream, eps, Lcbf, Zg);
  hipLaunchKernelGGL(k_decode,    dim3(2048), dim3(256), 0, stream, X, Zg, W1T, b1, W2T, b2, log_R, ll);
  hipLaunchKernelGGL(k_lse,       dim3(32),   dim3(64),  0, stream, ll, out);
}

// Round 3
// 153.245 us; speedup vs baseline: 1.1365x; 1.0768x over previous
//
#include <hip/hip_runtime.h>
#include <hip/hip_bf16.h>
#include <math.h>

#define B_ 32
#define S_ 64
#define T_ 256
#define L_ 8
#define D_ 128
#define H_ 128

typedef __attribute__((ext_vector_type(8))) short short8;
typedef __attribute__((ext_vector_type(4))) short short4v;
typedef __attribute__((ext_vector_type(4))) float float4v;
typedef __attribute__((ext_vector_type(4))) int int4v;

__device__ __forceinline__ short f2bf(float x) {
  __hip_bfloat16 h = __float2bfloat16(x);
  return *reinterpret_cast<short*>(&h);
}

// lane-uniform broadcast of lane `sl` (sl must be wave-uniform): v_readlane
__device__ __forceinline__ float rdlane(float x, int sl) {
  return __int_as_float(__builtin_amdgcn_readlane(__float_as_int(x), sl));
}
// shift down by one lane across the whole wave (DPP wave_shr:1);
// lane 0 receives `tailv` (old-value path, bound_ctrl=0)
__device__ __forceinline__ float dpp_shr1(float x, float tailv) {
  int r = __builtin_amdgcn_update_dpp(__float_as_int(tailv), __float_as_int(x),
                                      0x138, 0xF, 0xF, false);
  return __int_as_float(r);
}

// ---------------------------------------------------------------------------
// Stage A (+prep merged): blocks 0-7: Toeplitz-Schur Cholesky, one wave per
// latent l (serial coefficient chain -- the R2 software-pipelined variant
// produced NaN; reverted to this verified version). r = rsqrt(u^2-v^2) form.
// Blocks 8-71: weight conversion (H-permuted W1T; see k_decode).
// ---------------------------------------------------------------------------
__global__ __launch_bounds__(64) void k_chol_prep(
    const float* __restrict__ times, const float* __restrict__ log_taus,
    __hip_bfloat16* __restrict__ Lcbf_,
    const float* __restrict__ W1, const float* __restrict__ W2,
    __hip_bfloat16* __restrict__ W1T, __hip_bfloat16* __restrict__ W2T)
{
  __shared__ short panel[256][68];
  const int bi = blockIdx.x;
  const int j = threadIdx.x;

  if (bi >= 8) {
    const int base = (bi - 8) * 64 + j;          // 0..4095
    for (int idx = base; idx < H_ * D_; idx += 4096) {
      const int cc = idx >> 7, h = idx & 127;
      const int n = cc & 15, nt = cc >> 4;
      const int d = n * 8 + nt;
      W2T[(size_t)cc * H_ + h] = __float2bfloat16(W2[(size_t)h * D_ + d]);
    }
    for (int idx = base; idx < L_ * H_; idx += 4096) {
      const int li = idx >> 7, h = idx & 127;
      const int msrc = 32 * (h >> 5) + 2 * (h & 15) + ((h >> 4) & 1);
      W1T[(size_t)h * L_ + li] = __float2bfloat16(W1[(size_t)li * H_ + msrc]);
    }
    return;
  }

  const int l = bi;
  short* Lbf = (short*)Lcbf_ + (size_t)l * T_ * T_;

  const float tau = expf(log_taus[l]);
  const float inv2tau2 = 0.5f / (tau * tau);
  const float sig2 = 0.999f * 0.999f;
  const float t0 = times[0];

  const float c0 = sig2 + 1e-4f;
  const float isc0 = 1.0f / sqrtf(c0);

  float u[4], v[4];
#pragma unroll
  for (int c = 0; c < 4; ++c) {
    const int d = c * 64 + j;
    const float dt = times[d] - t0;
    float cv = sig2 * __expf(-dt * dt * inv2tau2);
    if (d == 0) cv = c0;
    u[c] = cv * isc0;
    v[c] = (d == 0) ? 0.0f : u[c];
  }

#pragma unroll
  for (int p = 0; p < 4; ++p) {
    for (int kk = 0; kk < 64; ++kk) {
      const float uk = rdlane(u[p], kk);
      const float vk = rdlane(v[p], kk);
      const float dd = fmaxf(__builtin_fmaf(uk, uk, -vk * vk), 1e-20f);
      const float rr = __builtin_amdgcn_rsqf(dd);
      const float s = uk * rr;
      const float sr = vk * rr;

      float up[4];
#pragma unroll
      for (int c = 0; c < 4; ++c) {
        if (c >= p) {
          const float uc = u[c], vc = v[c];
          up[c] = s * uc - sr * vc;
          v[c]  = s * vc - sr * uc;
          const float val = (c > p || j >= kk) ? up[c] : 0.0f;
          panel[(c - p) * 64 + j][kk] = f2bf(val);
        }
      }
#pragma unroll
      for (int c = 3; c >= 0; --c) {
        if (c >= p) {
          const float tail = (c > p) ? rdlane(up[c - 1], 63) : 0.0f;
          u[c] = dpp_shr1(up[c], tail);
        }
      }
    }
    __syncthreads();
    const int rpt = 256 - 64 * p;
    const int rsub = j >> 4, cp = (j & 15) * 4;
    for (int i0 = 0; i0 < rpt; i0 += 4) {
      const int pr = i0 + rsub;
      short4v vv = *(const short4v*)&panel[pr][cp];
      *(short4v*)&Lbf[((size_t)(p * 64 + pr) << 8) + p * 64 + cp] = vv;
    }
    __syncthreads();
  }
}

// ---------------------------------------------------------------------------
// Stage B: z GEMM via bf16 MFMA. Block = (l, bs-tile of 32) -> 512 blocks.
// Pair-balanced triangular tiles {w,15-w,7-w,8+w}: equal kc-sum per wave.
// Output Zg[l][bs][t]: acc transposed through the E LDS buffer after the
// K-loop, written as dense short8 stores. (Verified R1 version, unchanged.)
// ---------------------------------------------------------------------------
__global__ __launch_bounds__(256) void k_zgemm(
    const float* __restrict__ eps, const __hip_bfloat16* __restrict__ Lcbf_,
    __hip_bfloat16* __restrict__ Zg)
{
  __shared__ __align__(16) short E[32][264];
  const int bi = blockIdx.x;
  const int l = bi & 7, bs0 = (bi >> 3) * 32;
  const int tid = threadIdx.x, w = tid >> 6, lane = tid & 63;
  const int n = lane & 15, q = lane >> 4;
  const short* Lb = (const short*)Lcbf_ + (size_t)l * T_ * T_;

  // stage eps[bs0+row][l][:] -> E[row][:] bf16 (8 lanes cover a 1KB row)
  {
    const int row = tid >> 3, part = tid & 7;
    const float* src = eps + ((size_t)(bs0 + row) * L_ + l) * T_;
#pragma unroll
    for (int g = 0; g < 8; ++g) {
      const int c = (part + g * 8) * 4;
      float4v f = *(const float4v*)(src + c);
      short4v o;
#pragma unroll
      for (int jj = 0; jj < 4; ++jj) o[jj] = f2bf(f[jj]);
      *(short4v*)&E[row][c] = o;
    }
  }
  __syncthreads();

  float4v acc[4][2];
#pragma unroll
  for (int mi = 0; mi < 4; ++mi)
#pragma unroll
    for (int nt = 0; nt < 2; ++nt) acc[mi][nt] = (float4v){0.f, 0.f, 0.f, 0.f};

  // per-tile K bound: kc(t) = 32*ceil(16(t+1)/32); L rows beyond the
  // triangle are chol-written zeros inside this window.
  const int kmax = ((15 - w + 2) >> 1) << 5;      // w: 256,256,224,224
  for (int k0 = 0; k0 < kmax; k0 += 32) {
    short8 bfrg[2];
#pragma unroll
    for (int nt = 0; nt < 2; ++nt)
      bfrg[nt] = *(const short8*)&E[nt * 16 + n][k0 + q * 8];
#pragma unroll
    for (int mi = 0; mi < 4; ++mi) {
      const int tile = (mi == 0) ? w : (mi == 1) ? (15 - w) : (mi == 2) ? (7 - w) : (8 + w);
      const int kc = ((tile + 2) >> 1) << 5;
      if (k0 < kc) {
        const int u = tile * 16 + n;
        const short8 afr = *(const short8*)&Lb[((size_t)u << 8) + k0 + q * 8];
#pragma unroll
        for (int nt = 0; nt < 2; ++nt)
          acc[mi][nt] = __builtin_amdgcn_mfma_f32_16x16x32_bf16(afr, bfrg[nt], acc[mi][nt], 0, 0, 0);
      }
    }
  }
  __syncthreads();   // all waves done reading E -> reuse as transpose buffer

#pragma unroll
  for (int mi = 0; mi < 4; ++mi) {
    const int tile = (mi == 0) ? w : (mi == 1) ? (15 - w) : (mi == 2) ? (7 - w) : (8 + w);
#pragma unroll
    for (int nt = 0; nt < 2; ++nt) {
      short4v o;
#pragma unroll
      for (int r = 0; r < 4; ++r) o[r] = f2bf(acc[mi][nt][r]);
      *(short4v*)&E[nt * 16 + n][tile * 16 + q * 4] = o;
    }
  }
  __syncthreads();

  // dense coalesced copy: Zg[l][bs][t]
  {
    const int row = tid >> 3, part = tid & 7;
    short* dst = (short*)Zg + ((size_t)l * (B_ * S_) + bs0 + row) * T_;
#pragma unroll
    for (int g = 0; g < 4; ++g) {
      const int c = (g * 8 + part) * 8;
      *(short8*)&dst[c] = *(const short8*)&E[row][c];
    }
  }
}

// ---------------------------------------------------------------------------
// Stages C-F fused: one block per (b,s). launch_bounds (256,4): R1's (256,7)
// forced ~48B/thread scratch spill (24.6 MB WRITE_SIZE, VGPR 52->36) -- LDS
// at 21.5 KB already allows 7 blocks/CU by the LDS limit, and ~52 VGPR
// allows 8 waves/SIMD, so the cap only hurt. Bijective XCD chunk swizzle:
// each XCD owns 256 consecutive bs (4 b-slices of X = 512 KB + 1 MB Zg
// resident in its L2 -> X fetched ~once instead of once per XCD).
// hS quarter-phased [64][136]; packed bf16x2 h-store; exp2-folded tanh.
// ---------------------------------------------------------------------------
__global__ __launch_bounds__(256, 4) void k_decode(
    const float* __restrict__ X, const __hip_bfloat16* __restrict__ Zg,
    const __hip_bfloat16* __restrict__ W1T, const float* __restrict__ b1,
    const __hip_bfloat16* __restrict__ W2T, const float* __restrict__ b2,
    const float* __restrict__ log_R, float* __restrict__ ll)
{
  __shared__ __align__(16) short Zt[256][8];
  __shared__ __align__(16) __hip_bfloat16 hS[64][136];
  __shared__ float redbuf[4];

  const int bid = blockIdx.x;
  const int bs = (bid & 7) * 256 + (bid >> 3);   // XCD-chunked (2048%8==0)
  const int b = bs >> 6;
  const int tid = threadIdx.x;
  const int w = tid >> 6, lane = tid & 63;
  const int n = lane & 15, q = lane >> 4;
  const unsigned short* Zs = (const unsigned short*)Zg;
  const short* W1s = (const short*)W1T;
  const short* W2s = (const short*)W2T;

  // gather Z[t=tid][l=0..7] from [l][bs][t] (each load coalesced 512B/wave)
  {
    const size_t base = (size_t)bs * T_ + tid;
    const size_t lstr = (size_t)(B_ * S_) * T_;
    unsigned int p0 = (unsigned int)Zs[base]            | ((unsigned int)Zs[base + lstr]     << 16);
    unsigned int p1 = (unsigned int)Zs[base + 2 * lstr] | ((unsigned int)Zs[base + 3 * lstr] << 16);
    unsigned int p2 = (unsigned int)Zs[base + 4 * lstr] | ((unsigned int)Zs[base + 5 * lstr] << 16);
    unsigned int p3 = (unsigned int)Zs[base + 6 * lstr] | ((unsigned int)Zs[base + 7 * lstr] << 16);
    int4v zi = {(int)p0, (int)p1, (int)p2, (int)p3};
    *(int4v*)&Zt[tid][0] = zi;
  }

  float sLR = log_R[lane] + log_R[lane + 64];
#pragma unroll
  for (int off = 32; off >= 1; off >>= 1) sLR += __shfl_xor(sLR, off);

  const float L22 = 2.8853900817779268f;   // 2*log2(e)
  const int d0 = n * 8 + 2 * w;
  const int hc = 32 * w + 2 * n;           // physical hS column pair base
  float invr2[2], b22[2], pb[2];
#pragma unroll
  for (int jj = 0; jj < 2; ++jj) {
    invr2[jj] = expf(-log_R[d0 + jj]);
    b22[jj] = b2[d0 + jj];
    pb[jj] = b1[hc + jj] * L22;
  }

  const short8 zero8 = {0, 0, 0, 0, 0, 0, 0, 0};
  short8 w1f[2];
  short8 bfr[2][4];
#pragma unroll
  for (int jj = 0; jj < 2; ++jj) {
    const int c = (2 * w + jj) * 16 + n;
    short8 v = zero8;
    if (q == 0) v = *(const short8*)&W1s[(size_t)c * L_];
    w1f[jj] = v;
#pragma unroll
    for (int ks = 0; ks < 4; ++ks)
      bfr[jj][ks] = *(const short8*)&W2s[(size_t)c * H_ + ks * 32 + q * 8];
  }

  float qsum = 0.0f;
  __syncthreads();   // Zt ready

#pragma unroll 1
  for (int qtr = 0; qtr < 4; ++qtr) {
    short* hp = (short*)hS + (q * 4) * 136 + hc;
#pragma unroll 1
    for (int mi = 0; mi < 4; ++mi) {
      short8 zf = zero8;
      if (q == 0) zf = *(const short8*)&Zt[qtr * 64 + mi * 16 + n][0];
      float4v c0 = __builtin_amdgcn_mfma_f32_16x16x32_bf16(zf, w1f[0], (float4v){0.f,0.f,0.f,0.f}, 0, 0, 0);
      float4v c1 = __builtin_amdgcn_mfma_f32_16x16x32_bf16(zf, w1f[1], (float4v){0.f,0.f,0.f,0.f}, 0, 0, 0);
#pragma unroll
      for (int r = 0; r < 4; ++r) {
        const float a0 = __builtin_fmaf(c0[r], L22, pb[0]);
        const float a1 = __builtin_fmaf(c1[r], L22, pb[1]);
        const float p0 = __builtin_amdgcn_exp2f(a0) + 1.f;
        const float p1 = __builtin_amdgcn_exp2f(a1) + 1.f;
        const float rj = __builtin_amdgcn_rcpf(p0 * p1);
        const float h0 = __builtin_fmaf(-2.f * p1, rj, 1.f);
        const float h1 = __builtin_fmaf(-2.f * p0, rj, 1.f);
        float2 hv2; hv2.x = h0; hv2.y = h1;
        *reinterpret_cast<__hip_bfloat162*>(hp + r * 136) = __float22bfloat162_rn(hv2);
      }
      hp += 16 * 136;
    }
    __syncthreads();
#pragma unroll 1
    for (int mi = 0; mi < 4; ++mi) {
      short8 af[4];
#pragma unroll
      for (int ks = 0; ks < 4; ++ks)
        af[ks] = *(const short8*)&hS[mi * 16 + n][ks * 32 + q * 8];
      float4v acc0 = (float4v){0.f, 0.f, 0.f, 0.f};
      float4v acc1 = (float4v){0.f, 0.f, 0.f, 0.f};
#pragma unroll
      for (int ks = 0; ks < 4; ++ks) {
        acc0 = __builtin_amdgcn_mfma_f32_16x16x32_bf16(af[ks], bfr[0][ks], acc0, 0, 0, 0);
        acc1 = __builtin_amdgcn_mfma_f32_16x16x32_bf16(af[ks], bfr[1][ks], acc1, 0, 0, 0);
      }
      const int tbase = qtr * 64 + mi * 16 + q * 4;
#pragma unroll
      for (int r = 0; r < 4; ++r) {
        const int t = tbase + r;
        const float2 xv = *(const float2*)(X + (((size_t)b << 8) + t) * D_ + d0);
        float diff0 = xv.x - (acc0[r] + b22[0]);
        float diff1 = xv.y - (acc1[r] + b22[1]);
        qsum += diff0 * diff0 * invr2[0] + diff1 * diff1 * invr2[1];
      }
    }
    __syncthreads();
  }

#pragma unroll
  for (int off = 32; off >= 1; off >>= 1) qsum += __shfl_xor(qsum, off);
  if (lane == 0) redbuf[w] = qsum;
  __syncthreads();
  if (tid == 0) {
    float Q = redbuf[0] + redbuf[1] + redbuf[2] + redbuf[3];
    float log_norm = 0.5f * (sLR + (float)D_ * 1.8378770664093453f);
    ll[bs] = -0.5f * Q - (float)T_ * log_norm;
  }
}

// ---------------------------------------------------------------------------
// Final: nll[b] = -(logsumexp_s(ll) - log S). One wave per b.
// ---------------------------------------------------------------------------
__global__ __launch_bounds__(64) void k_lse(
    const float* __restrict__ ll, float* __restrict__ out)
{
  const int b = blockIdx.x;
  const int s = threadIdx.x;
  float v = ll[b * 64 + s];
  float m = v;
#pragma unroll
  for (int off = 32; off >= 1; off >>= 1) m = fmaxf(m, __shfl_xor(m, off));
  float e = __expf(v - m);
#pragma unroll
  for (int off = 32; off >= 1; off >>= 1) e += __shfl_xor(e, off);
  if (s == 0) out[b] = -(m + __logf(e) - 4.1588830833596715f);
}

extern "C" void kernel_launch(void* const* d_in, const int* in_sizes, int n_in,
                              void* d_out, int out_size, void* d_ws, size_t ws_size,
                              hipStream_t stream) {
  const float* X        = (const float*)d_in[0];
  const float* times    = (const float*)d_in[1];
  const float* log_taus = (const float*)d_in[2];
  const float* log_R    = (const float*)d_in[3];
  const float* W1       = (const float*)d_in[4];
  const float* b1       = (const float*)d_in[5];
  const float* W2       = (const float*)d_in[6];
  const float* b2       = (const float*)d_in[7];
  const float* eps      = (const float*)d_in[8];
  float* out = (float*)d_out;

  char* ws = (char*)d_ws;
  __hip_bfloat16* Lcbf = (__hip_bfloat16*)(ws);                // 1 MiB bf16 [L][T][T]
  __hip_bfloat16* Zg   = (__hip_bfloat16*)(ws + 1048576);      // 8 MiB bf16 [L][BS][T]
  float* ll            = (float*)(ws + 9437184);               // 8 KiB
  __hip_bfloat16* W2T  = (__hip_bfloat16*)(ws + 9445376);      // 32 KiB
  __hip_bfloat16* W1T  = (__hip_bfloat16*)(ws + 9478144);      // 2 KiB

  hipLaunchKernelGGL(k_chol_prep, dim3(72),   dim3(64),  0, stream,
                     times, log_taus, Lcbf, W1, W2, W1T, W2T);
  hipLaunchKernelGGL(k_zgemm,     dim3(512),  dim3(256), 0, stream, eps, Lcbf, Zg);
  hipLaunchKernelGGL(k_decode,    dim3(2048), dim3(256), 0, stream, X, Zg, W1T, b1, W2T, b2, log_R, ll);
  hipLaunchKernelGGL(k_lse,       dim3(32),   dim3(64),  0, stream, ll, out);
}